// Round 3
// baseline (654.133 us; speedup 1.0000x reference)
//
#include <hip/hip_runtime.h>
#include <hip/hip_bf16.h>

#define NN 50000
#define EE 800000
#define DD 256
#define BF 128      // B*F
#define HC 96       // H*B*A
#define GG 64
#define NT 14       // (BF+HC)/16
#define KCN 8       // 256/32 k-chunks
#define NB 49       // ceil(NN/1024)

typedef short s16x8 __attribute__((ext_vector_type(8)));
typedef float f32x4 __attribute__((ext_vector_type(4)));

static __device__ __forceinline__ float b2f(unsigned u) {
    unsigned x = u << 16;
    float f;
    __builtin_memcpy(&f, &x, 4);
    return f;
}
static __device__ __forceinline__ unsigned short f2b(float f) {
    unsigned x;
    __builtin_memcpy(&x, &f, 4);
    unsigned lsb = (x >> 16) & 1u;
    x += 0x7fffu + lsb;           // round-to-nearest-even
    return (unsigned short)(x >> 16);
}

// ---------------- dtype detection ----------------
// Little-endian f32: u16[2i] = LOW mantissa half -> uniform-random "exponent";
// u16[2i+1] = high half (looks like valid bf16). Sample EVEN indices: genuine
// bf16 data has sane exponents there; f32 data shows ~84% wild exponents.
__global__ void k_detect(const unsigned short* node_u16, int* flag) {
    __shared__ int cnt;
    if (threadIdx.x == 0) cnt = 0;
    __syncthreads();
    int local = 0;
    #pragma unroll
    for (int j = 0; j < 4; j++) {
        int idx = 2 * (threadIdx.x * 4 + j);   // EVEN elements
        unsigned short u = node_u16[idx];
        int e = (u >> 7) & 0xFF;
        if (e < 100 || e > 140) local++;
    }
    atomicAdd(&cnt, local);
    __syncthreads();
    if (threadIdx.x == 0) flag[0] = (cnt > 256) ? 1 : 0;   // 1 = f32 buffers
}

// ---------------- small params -> f32 ----------------
__global__ void k_prep(const int* flag, const void* bcomb, const void* cbias,
                       const void* gw, const void* gb, const void* gms,
                       float* bcombF, float* cbiasF, float* gwF, float* gbF, float* gmsF) {
    int d = threadIdx.x;
    int isf = flag[0];
    auto rd = [&](const void* p, int i) -> float {
        return isf ? ((const float*)p)[i] : b2f(((const unsigned short*)p)[i]);
    };
    if (d < HC) bcombF[d] = rd(bcomb, d);
    cbiasF[d] = rd(cbias, d);
    gwF[d] = rd(gw, d);
    gbF[d] = rd(gb, d);
    gmsF[d] = rd(gms, d);
}

// ---------------- init ----------------
__global__ void k_init(int* deg, int* cursor, int* gcount, float* gsum, float* gsq) {
    int i = blockIdx.x * 256 + threadIdx.x;
    if (i < NN) { deg[i] = 1; cursor[i] = 0; }   // deg=1: self-loop
    if (i < GG) gcount[i] = 0;
    if (i < GG * DD) { gsum[i] = 0.f; gsq[i] = 0.f; }
}

// ---------------- histograms ----------------
__global__ void k_hist(const int* ei, const int* batch, int* deg, int* gcount) {
    int i = blockIdx.x * 256 + threadIdx.x;
    if (i < EE) atomicAdd(&deg[ei[EE + i]], 1);   // dst row
    if (i < NN) atomicAdd(&gcount[batch[i]], 1);
}

// ---------------- scan ----------------
__global__ void k_scan1(const int* deg, int* bsum) {
    __shared__ int lds[256];
    int b = blockIdx.x, t = threadIdx.x;
    int base = b * 1024 + t * 4;
    int s = 0;
    #pragma unroll
    for (int j = 0; j < 4; j++) { int idx = base + j; if (idx < NN) s += deg[idx]; }
    lds[t] = s; __syncthreads();
    for (int ofs = 128; ofs > 0; ofs >>= 1) {
        if (t < ofs) lds[t] += lds[t + ofs];
        __syncthreads();
    }
    if (t == 0) bsum[b] = lds[0];
}

__global__ void k_scan2(const int* bsum, int* bpre, const int* gcount, int* goff, int* row_off) {
    if (threadIdx.x == 0) {
        int r = 0;
        for (int i = 0; i < NB; i++) { bpre[i] = r; r += bsum[i]; }
        row_off[NN] = r;
    } else if (threadIdx.x == 1) {
        int r = 0;
        for (int g = 0; g < GG; g++) { goff[g] = r; r += gcount[g]; }
        goff[GG] = r;
    }
}

__global__ void k_scan3(const int* deg, const int* bpre, int* row_off, float* dinv) {
    __shared__ int lds[256];
    int b = blockIdx.x, t = threadIdx.x;
    int base = b * 1024 + t * 4;
    int d[4]; int s = 0;
    #pragma unroll
    for (int j = 0; j < 4; j++) { int idx = base + j; d[j] = (idx < NN) ? deg[idx] : 0; s += d[j]; }
    lds[t] = s; __syncthreads();
    for (int ofs = 1; ofs < 256; ofs <<= 1) {
        int add = (t >= ofs) ? lds[t - ofs] : 0;
        __syncthreads();
        lds[t] += add;
        __syncthreads();
    }
    int excl = lds[t] - s + bpre[b];
    #pragma unroll
    for (int j = 0; j < 4; j++) {
        int idx = base + j;
        if (idx < NN) {
            row_off[idx] = excl;
            excl += d[j];
            dinv[idx] = rsqrtf((float)deg[idx]);
        }
    }
}

// ---------------- CSR scatter ----------------
__global__ void k_scatter(const int* ei, const int* row_off, int* cursor, int* csr) {
    int i = blockIdx.x * 256 + threadIdx.x;
    if (i >= EE + NN) return;
    int s, dnode;
    if (i < EE) { s = ei[i]; dnode = ei[EE + i]; }
    else { s = i - EE; dnode = s; }
    int pos = row_off[dnode] + atomicAdd(&cursor[dnode], 1);
    csr[pos] = s;
}

// ---------------- pack W (bases|comb) into MFMA B-fragment layout ----------------
__global__ void k_pack(const int* flag, const void* Wb, const void* Wc, unsigned short* wpack) {
    int t = blockIdx.x, kc = blockIdx.y, lane = threadIdx.x;
    int isf = flag[0];
    int n = t * 16 + (lane & 15);
    int kb = kc * 32 + (lane >> 4) * 8;
    unsigned short* o = wpack + (size_t)(((t * KCN) + kc) * 64 + lane) * 8;
    #pragma unroll
    for (int j = 0; j < 8; j++) {
        int k = kb + j;
        int src = (n < BF) ? (k * BF + n) : (k * HC + (n - BF));
        const void* W = (n < BF) ? Wb : Wc;
        o[j] = isf ? f2b(((const float*)W)[src]) : ((const unsigned short*)W)[src];
    }
}

// ---------------- fused GEMM -> bases[N,128] bf16 + comb[N,96] f32 ----------------
__global__ __launch_bounds__(256) void k_gemm(const int* flag, const void* node,
                                              const unsigned short* wpack, const float* bcombF,
                                              unsigned short* bases, float* comb) {
    int wv = threadIdx.x >> 6, lane = threadIdx.x & 63;
    int row0 = blockIdx.x * 64 + wv * 16;
    int m = row0 + (lane & 15);
    int mc = m < NN ? m : NN - 1;
    int kg = lane >> 4;
    int isf = flag[0];
    const s16x8* bp = reinterpret_cast<const s16x8*>(wpack);
    f32x4 acc[NT];
    #pragma unroll
    for (int t = 0; t < NT; t++) acc[t] = (f32x4){0.f, 0.f, 0.f, 0.f};
    if (isf) {
        const float* nf = (const float*)node + (size_t)mc * DD;
        for (int kc = 0; kc < KCN; kc++) {
            union { s16x8 v; unsigned short e[8]; } a;
            const float* src = nf + kc * 32 + kg * 8;
            #pragma unroll
            for (int j = 0; j < 8; j++) a.e[j] = f2b(src[j]);
            #pragma unroll
            for (int t = 0; t < NT; t++) {
                s16x8 b = bp[(size_t)(t * KCN + kc) * 64 + lane];
                acc[t] = __builtin_amdgcn_mfma_f32_16x16x32_bf16(a.v, b, acc[t], 0, 0, 0);
            }
        }
    } else {
        const s16x8* ap = reinterpret_cast<const s16x8*>(node);
        for (int kc = 0; kc < KCN; kc++) {
            s16x8 a = ap[(size_t)mc * 32 + kc * 4 + kg];
            #pragma unroll
            for (int t = 0; t < NT; t++) {
                s16x8 b = bp[(size_t)(t * KCN + kc) * 64 + lane];
                acc[t] = __builtin_amdgcn_mfma_f32_16x16x32_bf16(a, b, acc[t], 0, 0, 0);
            }
        }
    }
    int colb = lane & 15;
    #pragma unroll
    for (int t = 0; t < NT; t++) {
        int nc = t * 16 + colb;
        #pragma unroll
        for (int i = 0; i < 4; i++) {
            int r = row0 + kg * 4 + i;
            if (r < NN) {
                float v = acc[t][i];
                if (nc < BF) bases[(size_t)r * BF + nc] = f2b(v);
                else comb[(size_t)r * HC + (nc - BF)] = v + bcombF[nc - BF];
            }
        }
    }
}

// ---------------- per-node aggregation + einsum -> h (staged in d_out) ----------------
__global__ __launch_bounds__(256) void k_agg(const int* flag, const unsigned short* bases,
                                             const float* comb, const float* dinv,
                                             const int* row_off, const int* csr,
                                             const float* cbiasF, void* hout) {
    __shared__ float2 lds[4][3][64];
    int wv = threadIdx.x >> 6, lane = threadIdx.x & 63;
    int v = blockIdx.x * 4 + wv;          // NN % 4 == 0
    int r0 = row_off[v], r1 = row_off[v + 1];
    float dv = dinv[v];
    const unsigned* bp = reinterpret_cast<const unsigned*>(bases);
    float2 asym = {0.f, 0.f}, asum = {0.f, 0.f}, amax = {-3.4e38f, -3.4e38f};
    for (int e = r0; e < r1; e++) {
        int s = csr[e];
        float w = dinv[s] * dv;
        unsigned mg = bp[(size_t)s * 64 + lane];
        float m0 = b2f(mg & 0xffffu), m1 = b2f(mg >> 16);
        asym.x += w * m0; asym.y += w * m1;
        asum.x += m0;     asum.y += m1;
        amax.x = fmaxf(amax.x, m0); amax.y = fmaxf(amax.y, m1);
    }
    lds[wv][0][lane] = asym;
    lds[wv][1][lane] = asum;
    lds[wv][2][lane] = amax;
    __syncthreads();
    const float* P0 = (const float*)&lds[wv][0][0];
    const float* P1 = (const float*)&lds[wv][1][0];
    const float* P2 = (const float*)&lds[wv][2][0];
    int d0 = lane * 4;
    int hh = d0 >> 5;
    float cb[12];
    #pragma unroll
    for (int k = 0; k < 12; k++) cb[k] = comb[(size_t)v * HC + hh * 12 + k];
    float y[4];
    #pragma unroll
    for (int i = 0; i < 4; i++) {
        int d = d0 + i, f = d & 31;
        float acc = cbiasF[d];
        #pragma unroll
        for (int k = 0; k < 12; k++) {
            int a = k >> 2, b = k & 3;
            const float* P = (a == 0) ? P0 : ((a == 1) ? P1 : P2);
            acc += cb[k] * P[b * 32 + f];
        }
        y[i] = acc;
    }
    if (flag[0]) {
        f32x4 o = {y[0], y[1], y[2], y[3]};
        reinterpret_cast<f32x4*>(hout)[(size_t)v * 64 + lane] = o;
    } else {
        union { unsigned short e[4]; uint2 u; } o;
        #pragma unroll
        for (int i = 0; i < 4; i++) o.e[i] = f2b(y[i]);
        reinterpret_cast<uint2*>(hout)[(size_t)v * 64 + lane] = o.u;
    }
}

// ---------------- GraphNorm stats pass 1: chunked Σh, Σh² ----------------
__global__ void k_stats1(const int* flag, const void* h, const int* batch, float* gsum, float* gsq) {
    int t = threadIdx.x;
    int v0 = blockIdx.x * 128;
    int v1 = v0 + 128; if (v1 > NN) v1 = NN;
    int isf = flag[0];
    float sum = 0.f, sq = 0.f;
    int curg = batch[v0];
    for (int v = v0; v < v1; v++) {
        int g = batch[v];
        if (g != curg) {
            atomicAdd(&gsum[curg * DD + t], sum);
            atomicAdd(&gsq[curg * DD + t], sq);
            sum = 0.f; sq = 0.f; curg = g;
        }
        float x = isf ? ((const float*)h)[(size_t)v * DD + t]
                      : b2f(((const unsigned short*)h)[(size_t)v * DD + t]);
        sum += x; sq += x * x;
    }
    atomicAdd(&gsum[curg * DD + t], sum);
    atomicAdd(&gsq[curg * DD + t], sq);
}

// ---------------- GraphNorm stats pass 2 ----------------
__global__ void k_stats2(const float* gsum, const float* gsq, const int* goff,
                         const float* gwF, const float* gbF, const float* gmsF,
                         float* sA, float* sB) {
    int i = blockIdx.x * 256 + threadIdx.x;
    if (i >= GG * DD) return;
    int g = i >> 8, d = i & 255;
    int c = goff[g + 1] - goff[g];
    float cnt = (float)(c > 1 ? c : 1);
    float mu = gsum[i] / cnt;
    float m2 = gsq[i] / cnt;
    float al = gmsF[d];
    float var = m2 - mu * mu * (2.f * al - al * al);   // E[(h-al*mu)^2]
    float rstd = rsqrtf(var + 1e-5f);
    float sa = gwF[d] * rstd;
    sA[i] = sa;
    sB[i] = gbF[d] - sa * al * mu;
}

// ---------------- final normalize + ReLU (in place on d_out) ----------------
__global__ void k_out(const int* flag, const int* batch, const float* sA, const float* sB, void* out) {
    int tid = blockIdx.x * 256 + threadIdx.x;
    int v = tid >> 6, q = tid & 63;
    if (v >= NN) return;
    int g = batch[v];
    f32x4 a = reinterpret_cast<const f32x4*>(sA)[g * 64 + q];
    f32x4 b = reinterpret_cast<const f32x4*>(sB)[g * 64 + q];
    if (flag[0]) {
        f32x4 x = reinterpret_cast<const f32x4*>(out)[(size_t)v * 64 + q];
        f32x4 y;
        #pragma unroll
        for (int i = 0; i < 4; i++) y[i] = fmaxf(x[i] * a[i] + b[i], 0.f);
        reinterpret_cast<f32x4*>(out)[(size_t)v * 64 + q] = y;
    } else {
        uint2 xr = reinterpret_cast<const uint2*>(out)[(size_t)v * 64 + q];
        float x0 = b2f(xr.x & 0xffffu), x1 = b2f(xr.x >> 16);
        float x2 = b2f(xr.y & 0xffffu), x3 = b2f(xr.y >> 16);
        union { unsigned short e[4]; uint2 u; } o;
        o.e[0] = f2b(fmaxf(x0 * a[0] + b[0], 0.f));
        o.e[1] = f2b(fmaxf(x1 * a[1] + b[1], 0.f));
        o.e[2] = f2b(fmaxf(x2 * a[2] + b[2], 0.f));
        o.e[3] = f2b(fmaxf(x3 * a[3] + b[3], 0.f));
        reinterpret_cast<uint2*>(out)[(size_t)v * 64 + q] = o.u;
    }
}

extern "C" void kernel_launch(void* const* d_in, const int* in_sizes, int n_in,
                              void* d_out, int out_size, void* d_ws, size_t ws_size,
                              hipStream_t stream) {
    const void* node  = d_in[0];
    const void* Wb    = d_in[2];
    const void* Wc    = d_in[3];
    const void* bcomb = d_in[4];
    const void* cbias = d_in[5];
    const void* gw    = d_in[6];
    const void* gb    = d_in[7];
    const void* gms   = d_in[8];
    const int* ei     = (const int*)d_in[9];
    const int* batch  = (const int*)d_in[10];

    char* w = (char*)d_ws;
    size_t off = 0;
    auto alloc = [&](size_t bytes) -> void* {
        off = (off + 255) & ~(size_t)255;
        void* p = w + off;
        off += bytes;
        return p;
    };
    unsigned short* bases = (unsigned short*)alloc((size_t)NN * BF * 2);
    float* comb    = (float*)alloc((size_t)NN * HC * 4);
    int*   csr     = (int*)alloc((size_t)(EE + NN) * 4);
    int*   deg     = (int*)alloc((size_t)NN * 4);
    float* dinv    = (float*)alloc((size_t)NN * 4);
    int*   row_off = (int*)alloc((size_t)(NN + 1) * 4);
    int*   cursor  = (int*)alloc((size_t)NN * 4);
    int*   bsum    = (int*)alloc((size_t)NB * 4);
    int*   bpre    = (int*)alloc((size_t)NB * 4);
    int*   gcount  = (int*)alloc((size_t)GG * 4);
    int*   goff    = (int*)alloc((size_t)(GG + 1) * 4);
    float* gsum    = (float*)alloc((size_t)GG * DD * 4);
    float* gsq     = (float*)alloc((size_t)GG * DD * 4);
    float* sA      = (float*)alloc((size_t)GG * DD * 4);
    float* sB      = (float*)alloc((size_t)GG * DD * 4);
    unsigned short* wpack = (unsigned short*)alloc((size_t)NT * KCN * 64 * 8 * 2);
    int*   flag    = (int*)alloc(256);
    float* bcombF  = (float*)alloc(HC * 4);
    float* cbiasF  = (float*)alloc(DD * 4);
    float* gwF     = (float*)alloc(DD * 4);
    float* gbF     = (float*)alloc(DD * 4);
    float* gmsF    = (float*)alloc(DD * 4);

    k_detect<<<1, 256, 0, stream>>>((const unsigned short*)node, flag);
    k_prep<<<1, 256, 0, stream>>>(flag, bcomb, cbias, gw, gb, gms, bcombF, cbiasF, gwF, gbF, gmsF);
    k_init<<<(NN + 255) / 256, 256, 0, stream>>>(deg, cursor, gcount, gsum, gsq);
    k_hist<<<(EE + 255) / 256, 256, 0, stream>>>(ei, batch, deg, gcount);
    k_scan1<<<NB, 256, 0, stream>>>(deg, bsum);
    k_scan2<<<1, 64, 0, stream>>>(bsum, bpre, gcount, goff, row_off);
    k_scan3<<<NB, 256, 0, stream>>>(deg, bpre, row_off, dinv);
    k_scatter<<<(EE + NN + 255) / 256, 256, 0, stream>>>(ei, row_off, cursor, csr);
    k_pack<<<dim3(NT, KCN), 64, 0, stream>>>(flag, Wb, Wc, wpack);
    k_gemm<<<(NN + 63) / 64, 256, 0, stream>>>(flag, node, wpack, bcombF, bases, comb);
    k_agg<<<NN / 4, 256, 0, stream>>>(flag, bases, comb, dinv, row_off, csr, cbiasF, d_out);
    k_stats1<<<(NN + 127) / 128, 256, 0, stream>>>(flag, d_out, batch, gsum, gsq);
    k_stats2<<<GG, 256, 0, stream>>>(gsum, gsq, goff, gwF, gbF, gmsF, sA, sB);
    k_out<<<(NN * 64 + 255) / 256, 256, 0, stream>>>(flag, batch, sA, sB, d_out);
}

// Round 4
// 403.083 us; speedup vs baseline: 1.6228x; 1.6228x over previous
//
#include <hip/hip_runtime.h>
#include <hip/hip_bf16.h>

#define NN 50000
#define EE 800000
#define DD 256
#define BF 128      // B*F
#define HC 96       // H*B*A
#define GG 64
#define NT 14       // (BF+HC)/16
#define KCN 8       // 256/32 k-chunks
#define NB 49       // ceil(NN/1024)
#define RS 12500    // node-range size (NN/4)
#define RC 4        // node ranges
#define CS 12500    // edges per chunk (EE/64)
#define CC 64       // edge chunks

typedef short s16x8 __attribute__((ext_vector_type(8)));
typedef float f32x4 __attribute__((ext_vector_type(4)));

static __device__ __forceinline__ float b2f(unsigned u) {
    unsigned x = u << 16;
    float f;
    __builtin_memcpy(&f, &x, 4);
    return f;
}
static __device__ __forceinline__ unsigned short f2b(float f) {
    unsigned x;
    __builtin_memcpy(&x, &f, 4);
    unsigned lsb = (x >> 16) & 1u;
    x += 0x7fffu + lsb;           // round-to-nearest-even
    return (unsigned short)(x >> 16);
}

// ---------------- dtype detection (even u16 of f32 = mantissa garbage) ----------------
__global__ void k_detect(const unsigned short* node_u16, int* flag) {
    __shared__ int cnt;
    if (threadIdx.x == 0) cnt = 0;
    __syncthreads();
    int local = 0;
    #pragma unroll
    for (int j = 0; j < 4; j++) {
        int idx = 2 * (threadIdx.x * 4 + j);   // EVEN elements
        unsigned short u = node_u16[idx];
        int e = (u >> 7) & 0xFF;
        if (e < 100 || e > 140) local++;
    }
    atomicAdd(&cnt, local);
    __syncthreads();
    if (threadIdx.x == 0) flag[0] = (cnt > 256) ? 1 : 0;   // 1 = f32 buffers
}

// ---------------- small params -> f32 ----------------
__global__ void k_prep(const int* flag, const void* bcomb, const void* cbias,
                       const void* gw, const void* gb, const void* gms,
                       float* bcombF, float* cbiasF, float* gwF, float* gbF, float* gmsF) {
    int d = threadIdx.x;
    int isf = flag[0];
    auto rd = [&](const void* p, int i) -> float {
        return isf ? ((const float*)p)[i] : b2f(((const unsigned short*)p)[i]);
    };
    if (d < HC) bcombF[d] = rd(bcomb, d);
    cbiasF[d] = rd(cbias, d);
    gwF[d] = rd(gw, d);
    gbF[d] = rd(gb, d);
    gmsF[d] = rd(gms, d);
}

// ---------------- init (zero GraphNorm accumulators) ----------------
__global__ void k_init(float* gsum, float* gsq) {
    int i = blockIdx.x * 256 + threadIdx.x;
    if (i < GG * DD) { gsum[i] = 0.f; gsq[i] = 0.f; }
}

// ---------------- goff via binary search on sorted batch ----------------
__global__ void k_goff(const int* batch, int* goff) {
    int g = threadIdx.x;
    if (g > GG) return;
    int lo = 0, hi = NN;
    while (lo < hi) { int mid = (lo + hi) >> 1; if (batch[mid] < g) lo = mid + 1; else hi = mid; }
    goff[g] = lo;
}

// ---------------- per-(chunk,range) LDS histogram -> partial[c][n] ----------------
__global__ __launch_bounds__(256) void k_ehist(const int* ei, int* partial) {
    __shared__ int hist[RS];
    int c = blockIdx.x, r = blockIdx.y;
    for (int i = threadIdx.x; i < RS; i += 256) hist[i] = 0;
    __syncthreads();
    int base = r * RS;
    const int* dstp = ei + EE + (size_t)c * CS;
    for (int i = threadIdx.x; i < CS; i += 256) {
        int d = dstp[i] - base;
        if ((unsigned)d < RS) atomicAdd(&hist[d], 1);
    }
    __syncthreads();
    int* o = partial + (size_t)c * NN + base;
    for (int i = threadIdx.x; i < RS; i += 256) o[i] = hist[i];
}

// ---------------- per-node exclusive scan over chunks (in place) + deg ----------------
__global__ void k_colscan(int* partial, int* deg) {
    int n = blockIdx.x * 256 + threadIdx.x;
    if (n >= NN) return;
    int run = 0;
    for (int c = 0; c < CC; c++) {
        size_t idx = (size_t)c * NN + n;
        int v = partial[idx];
        partial[idx] = run;
        run += v;
    }
    deg[n] = run + 1;   // +1 self-loop
}

// ---------------- block scan for row_off ----------------
__global__ void k_scan1(const int* deg, int* bsum) {
    __shared__ int lds[256];
    int b = blockIdx.x, t = threadIdx.x;
    int base = b * 1024 + t * 4;
    int s = 0;
    #pragma unroll
    for (int j = 0; j < 4; j++) { int idx = base + j; if (idx < NN) s += deg[idx]; }
    lds[t] = s; __syncthreads();
    for (int ofs = 128; ofs > 0; ofs >>= 1) {
        if (t < ofs) lds[t] += lds[t + ofs];
        __syncthreads();
    }
    if (t == 0) bsum[b] = lds[0];
}

__global__ void k_scan2(const int* bsum, int* bpre, int* row_off) {
    if (threadIdx.x == 0) {
        int r = 0;
        for (int i = 0; i < NB; i++) { bpre[i] = r; r += bsum[i]; }
        row_off[NN] = r;
    }
}

__global__ void k_scan3(const int* deg, const int* bpre, int* row_off, float* dinv, int* csr) {
    __shared__ int lds[256];
    int b = blockIdx.x, t = threadIdx.x;
    int base = b * 1024 + t * 4;
    int d[4]; int s = 0;
    #pragma unroll
    for (int j = 0; j < 4; j++) { int idx = base + j; d[j] = (idx < NN) ? deg[idx] : 0; s += d[j]; }
    lds[t] = s; __syncthreads();
    for (int ofs = 1; ofs < 256; ofs <<= 1) {
        int add = (t >= ofs) ? lds[t - ofs] : 0;
        __syncthreads();
        lds[t] += add;
        __syncthreads();
    }
    int excl = lds[t] - s + bpre[b];
    #pragma unroll
    for (int j = 0; j < 4; j++) {
        int idx = base + j;
        if (idx < NN) {
            row_off[idx] = excl;
            csr[excl] = idx;             // self-loop occupies slot 0 of each row
            excl += d[j];
            dinv[idx] = rsqrtf((float)deg[idx]);
        }
    }
}

// ---------------- deterministic scatter: LDS cursors only ----------------
__global__ __launch_bounds__(256) void k_escatter(const int* ei, const int* row_off,
                                                  const int* partial, int* csr) {
    __shared__ int cur[RS];
    int c = blockIdx.x, r = blockIdx.y;
    int base = r * RS;
    const int* po = partial + (size_t)c * NN + base;
    const int* ro = row_off + base;
    for (int i = threadIdx.x; i < RS; i += 256) cur[i] = ro[i] + 1 + po[i];
    __syncthreads();
    const int* srcp = ei + (size_t)c * CS;
    const int* dstp = ei + EE + (size_t)c * CS;
    for (int i = threadIdx.x; i < CS; i += 256) {
        int d = dstp[i] - base;
        if ((unsigned)d < RS) {
            int slot = atomicAdd(&cur[d], 1);
            csr[slot] = srcp[i];
        }
    }
}

// ---------------- pack W (bases|comb) into MFMA B-fragment layout ----------------
__global__ void k_pack(const int* flag, const void* Wb, const void* Wc, unsigned short* wpack) {
    int t = blockIdx.x, kc = blockIdx.y, lane = threadIdx.x;
    int isf = flag[0];
    int n = t * 16 + (lane & 15);
    int kb = kc * 32 + (lane >> 4) * 8;
    unsigned short* o = wpack + (size_t)(((t * KCN) + kc) * 64 + lane) * 8;
    #pragma unroll
    for (int j = 0; j < 8; j++) {
        int k = kb + j;
        int src = (n < BF) ? (k * BF + n) : (k * HC + (n - BF));
        const void* W = (n < BF) ? Wb : Wc;
        o[j] = isf ? f2b(((const float*)W)[src]) : ((const unsigned short*)W)[src];
    }
}

// ---------------- fused GEMM -> bases[N,128] bf16 + comb[N,96] f32 ----------------
__global__ __launch_bounds__(256) void k_gemm(const int* flag, const void* node,
                                              const unsigned short* wpack, const float* bcombF,
                                              unsigned short* bases, float* comb) {
    int wv = threadIdx.x >> 6, lane = threadIdx.x & 63;
    int row0 = blockIdx.x * 64 + wv * 16;
    int m = row0 + (lane & 15);
    int mc = m < NN ? m : NN - 1;
    int kg = lane >> 4;
    int isf = flag[0];
    const s16x8* bp = reinterpret_cast<const s16x8*>(wpack);
    f32x4 acc[NT];
    #pragma unroll
    for (int t = 0; t < NT; t++) acc[t] = (f32x4){0.f, 0.f, 0.f, 0.f};
    if (isf) {
        const float* nf = (const float*)node + (size_t)mc * DD;
        for (int kc = 0; kc < KCN; kc++) {
            union { s16x8 v; unsigned short e[8]; } a;
            const float* src = nf + kc * 32 + kg * 8;
            #pragma unroll
            for (int j = 0; j < 8; j++) a.e[j] = f2b(src[j]);
            #pragma unroll
            for (int t = 0; t < NT; t++) {
                s16x8 b = bp[(size_t)(t * KCN + kc) * 64 + lane];
                acc[t] = __builtin_amdgcn_mfma_f32_16x16x32_bf16(a.v, b, acc[t], 0, 0, 0);
            }
        }
    } else {
        const s16x8* ap = reinterpret_cast<const s16x8*>(node);
        for (int kc = 0; kc < KCN; kc++) {
            s16x8 a = ap[(size_t)mc * 32 + kc * 4 + kg];
            #pragma unroll
            for (int t = 0; t < NT; t++) {
                s16x8 b = bp[(size_t)(t * KCN + kc) * 64 + lane];
                acc[t] = __builtin_amdgcn_mfma_f32_16x16x32_bf16(a, b, acc[t], 0, 0, 0);
            }
        }
    }
    int colb = lane & 15;
    #pragma unroll
    for (int t = 0; t < NT; t++) {
        int nc = t * 16 + colb;
        #pragma unroll
        for (int i = 0; i < 4; i++) {
            int r = row0 + kg * 4 + i;
            if (r < NN) {
                float v = acc[t][i];
                if (nc < BF) bases[(size_t)r * BF + nc] = f2b(v);
                else comb[(size_t)r * HC + (nc - BF)] = v + bcombF[nc - BF];
            }
        }
    }
}

// ---------------- per-node aggregation + einsum -> h (staged in d_out) ----------------
__global__ __launch_bounds__(256) void k_agg(const int* flag, const unsigned short* bases,
                                             const float* comb, const float* dinv,
                                             const int* row_off, const int* csr,
                                             const float* cbiasF, void* hout) {
    __shared__ float2 lds[4][3][64];
    int wv = threadIdx.x >> 6, lane = threadIdx.x & 63;
    int v = blockIdx.x * 4 + wv;          // NN % 4 == 0
    int r0 = row_off[v], r1 = row_off[v + 1];
    float dv = dinv[v];
    const unsigned* bp = reinterpret_cast<const unsigned*>(bases);
    float2 asym = {0.f, 0.f}, asum = {0.f, 0.f}, amax = {-3.4e38f, -3.4e38f};
    for (int e = r0; e < r1; e++) {
        int s = csr[e];
        float w = dinv[s] * dv;
        unsigned mg = bp[(size_t)s * 64 + lane];
        float m0 = b2f(mg & 0xffffu), m1 = b2f(mg >> 16);
        asym.x += w * m0; asym.y += w * m1;
        asum.x += m0;     asum.y += m1;
        amax.x = fmaxf(amax.x, m0); amax.y = fmaxf(amax.y, m1);
    }
    lds[wv][0][lane] = asym;
    lds[wv][1][lane] = asum;
    lds[wv][2][lane] = amax;
    __syncthreads();
    const float* P0 = (const float*)&lds[wv][0][0];
    const float* P1 = (const float*)&lds[wv][1][0];
    const float* P2 = (const float*)&lds[wv][2][0];
    int d0 = lane * 4;
    int hh = d0 >> 5;
    float cb[12];
    #pragma unroll
    for (int k = 0; k < 12; k++) cb[k] = comb[(size_t)v * HC + hh * 12 + k];
    float y[4];
    #pragma unroll
    for (int i = 0; i < 4; i++) {
        int d = d0 + i, f = d & 31;
        float acc = cbiasF[d];
        #pragma unroll
        for (int k = 0; k < 12; k++) {
            int a = k >> 2, b = k & 3;
            const float* P = (a == 0) ? P0 : ((a == 1) ? P1 : P2);
            acc += cb[k] * P[b * 32 + f];
        }
        y[i] = acc;
    }
    if (flag[0]) {
        f32x4 o = {y[0], y[1], y[2], y[3]};
        reinterpret_cast<f32x4*>(hout)[(size_t)v * 64 + lane] = o;
    } else {
        union { unsigned short e[4]; uint2 u; } o;
        #pragma unroll
        for (int i = 0; i < 4; i++) o.e[i] = f2b(y[i]);
        reinterpret_cast<uint2*>(hout)[(size_t)v * 64 + lane] = o.u;
    }
}

// ---------------- GraphNorm stats pass 1 ----------------
__global__ void k_stats1(const int* flag, const void* h, const int* batch, float* gsum, float* gsq) {
    int t = threadIdx.x;
    int v0 = blockIdx.x * 128;
    int v1 = v0 + 128; if (v1 > NN) v1 = NN;
    int isf = flag[0];
    float sum = 0.f, sq = 0.f;
    int curg = batch[v0];
    for (int v = v0; v < v1; v++) {
        int g = batch[v];
        if (g != curg) {
            atomicAdd(&gsum[curg * DD + t], sum);
            atomicAdd(&gsq[curg * DD + t], sq);
            sum = 0.f; sq = 0.f; curg = g;
        }
        float x = isf ? ((const float*)h)[(size_t)v * DD + t]
                      : b2f(((const unsigned short*)h)[(size_t)v * DD + t]);
        sum += x; sq += x * x;
    }
    atomicAdd(&gsum[curg * DD + t], sum);
    atomicAdd(&gsq[curg * DD + t], sq);
}

// ---------------- GraphNorm stats pass 2 ----------------
__global__ void k_stats2(const float* gsum, const float* gsq, const int* goff,
                         const float* gwF, const float* gbF, const float* gmsF,
                         float* sA, float* sB) {
    int i = blockIdx.x * 256 + threadIdx.x;
    if (i >= GG * DD) return;
    int g = i >> 8, d = i & 255;
    int c = goff[g + 1] - goff[g];
    float cnt = (float)(c > 1 ? c : 1);
    float mu = gsum[i] / cnt;
    float m2 = gsq[i] / cnt;
    float al = gmsF[d];
    float var = m2 - mu * mu * (2.f * al - al * al);   // E[(h-al*mu)^2]
    float rstd = rsqrtf(var + 1e-5f);
    float sa = gwF[d] * rstd;
    sA[i] = sa;
    sB[i] = gbF[d] - sa * al * mu;
}

// ---------------- final normalize + ReLU (in place on d_out) ----------------
__global__ void k_out(const int* flag, const int* batch, const float* sA, const float* sB, void* out) {
    int tid = blockIdx.x * 256 + threadIdx.x;
    int v = tid >> 6, q = tid & 63;
    if (v >= NN) return;
    int g = batch[v];
    f32x4 a = reinterpret_cast<const f32x4*>(sA)[g * 64 + q];
    f32x4 b = reinterpret_cast<const f32x4*>(sB)[g * 64 + q];
    if (flag[0]) {
        f32x4 x = reinterpret_cast<const f32x4*>(out)[(size_t)v * 64 + q];
        f32x4 y;
        #pragma unroll
        for (int i = 0; i < 4; i++) y[i] = fmaxf(x[i] * a[i] + b[i], 0.f);
        reinterpret_cast<f32x4*>(out)[(size_t)v * 64 + q] = y;
    } else {
        uint2 xr = reinterpret_cast<const uint2*>(out)[(size_t)v * 64 + q];
        float x0 = b2f(xr.x & 0xffffu), x1 = b2f(xr.x >> 16);
        float x2 = b2f(xr.y & 0xffffu), x3 = b2f(xr.y >> 16);
        union { unsigned short e[4]; uint2 u; } o;
        o.e[0] = f2b(fmaxf(x0 * a[0] + b[0], 0.f));
        o.e[1] = f2b(fmaxf(x1 * a[1] + b[1], 0.f));
        o.e[2] = f2b(fmaxf(x2 * a[2] + b[2], 0.f));
        o.e[3] = f2b(fmaxf(x3 * a[3] + b[3], 0.f));
        reinterpret_cast<uint2*>(out)[(size_t)v * 64 + q] = o.u;
    }
}

extern "C" void kernel_launch(void* const* d_in, const int* in_sizes, int n_in,
                              void* d_out, int out_size, void* d_ws, size_t ws_size,
                              hipStream_t stream) {
    const void* node  = d_in[0];
    const void* Wb    = d_in[2];
    const void* Wc    = d_in[3];
    const void* bcomb = d_in[4];
    const void* cbias = d_in[5];
    const void* gw    = d_in[6];
    const void* gb    = d_in[7];
    const void* gms   = d_in[8];
    const int* ei     = (const int*)d_in[9];
    const int* batch  = (const int*)d_in[10];

    char* w = (char*)d_ws;
    size_t off = 0;
    auto alloc = [&](size_t bytes) -> void* {
        off = (off + 255) & ~(size_t)255;
        void* p = w + off;
        off += bytes;
        return p;
    };
    unsigned short* bases = (unsigned short*)alloc((size_t)NN * BF * 2);
    float* comb    = (float*)alloc((size_t)NN * HC * 4);
    int*   csr     = (int*)alloc((size_t)(EE + NN) * 4);
    int*   partial = (int*)alloc((size_t)CC * NN * 4);
    int*   deg     = (int*)alloc((size_t)NN * 4);
    float* dinv    = (float*)alloc((size_t)NN * 4);
    int*   row_off = (int*)alloc((size_t)(NN + 1) * 4);
    int*   bsum    = (int*)alloc((size_t)NB * 4);
    int*   bpre    = (int*)alloc((size_t)NB * 4);
    int*   goff    = (int*)alloc((size_t)(GG + 1) * 4);
    float* gsum    = (float*)alloc((size_t)GG * DD * 4);
    float* gsq     = (float*)alloc((size_t)GG * DD * 4);
    float* sA      = (float*)alloc((size_t)GG * DD * 4);
    float* sB      = (float*)alloc((size_t)GG * DD * 4);
    unsigned short* wpack = (unsigned short*)alloc((size_t)NT * KCN * 64 * 8 * 2);
    int*   flag    = (int*)alloc(256);
    float* bcombF  = (float*)alloc(HC * 4);
    float* cbiasF  = (float*)alloc(DD * 4);
    float* gwF     = (float*)alloc(DD * 4);
    float* gbF     = (float*)alloc(DD * 4);
    float* gmsF    = (float*)alloc(DD * 4);

    k_detect<<<1, 256, 0, stream>>>((const unsigned short*)node, flag);
    k_prep<<<1, 256, 0, stream>>>(flag, bcomb, cbias, gw, gb, gms, bcombF, cbiasF, gwF, gbF, gmsF);
    k_init<<<(GG * DD + 255) / 256, 256, 0, stream>>>(gsum, gsq);
    k_goff<<<1, 128, 0, stream>>>(batch, goff);
    k_ehist<<<dim3(CC, RC), 256, 0, stream>>>(ei, partial);
    k_colscan<<<(NN + 255) / 256, 256, 0, stream>>>(partial, deg);
    k_scan1<<<NB, 256, 0, stream>>>(deg, bsum);
    k_scan2<<<1, 64, 0, stream>>>(bsum, bpre, row_off);
    k_scan3<<<NB, 256, 0, stream>>>(deg, bpre, row_off, dinv, csr);
    k_escatter<<<dim3(CC, RC), 256, 0, stream>>>(ei, row_off, partial, csr);
    k_pack<<<dim3(NT, KCN), 64, 0, stream>>>(flag, Wb, Wc, wpack);
    k_gemm<<<(NN + 63) / 64, 256, 0, stream>>>(flag, node, wpack, bcombF, bases, comb);
    k_agg<<<NN / 4, 256, 0, stream>>>(flag, bases, comb, dinv, row_off, csr, cbiasF, d_out);
    k_stats1<<<(NN + 127) / 128, 256, 0, stream>>>(flag, d_out, batch, gsum, gsq);
    k_stats2<<<GG, 256, 0, stream>>>(gsum, gsq, goff, gwF, gbF, gmsF, sA, sB);
    k_out<<<(NN * 64 + 255) / 256, 256, 0, stream>>>(flag, batch, sA, sB, d_out);
}

// Round 5
// 311.964 us; speedup vs baseline: 2.0968x; 1.2921x over previous
//
#include <hip/hip_runtime.h>
#include <hip/hip_bf16.h>

#define NN 50000
#define EE 800000
#define DD 256
#define BF 128      // B*F
#define HC 96       // H*B*A
#define GG 64
#define NT 14       // (BF+HC)/16
#define KCN 8       // 256/32 k-chunks
#define NB 49       // ceil(NN/1024)
#define RS 12500    // node-range size (NN/4)
#define RC 4        // node ranges
#define CS 12500    // edges per chunk (EE/64)
#define CC 64       // edge chunks
#define SL 8        // stats slices per graph

typedef short s16x8 __attribute__((ext_vector_type(8)));
typedef float f32x4 __attribute__((ext_vector_type(4)));

static __device__ __forceinline__ float b2f(unsigned u) {
    unsigned x = u << 16;
    float f;
    __builtin_memcpy(&f, &x, 4);
    return f;
}
static __device__ __forceinline__ unsigned short f2b(float f) {
    unsigned x;
    __builtin_memcpy(&x, &f, 4);
    unsigned lsb = (x >> 16) & 1u;
    x += 0x7fffu + lsb;           // round-to-nearest-even
    return (unsigned short)(x >> 16);
}
static __device__ __forceinline__ unsigned pack_trunc(float lo, float hi) {
    unsigned ulo, uhi;
    __builtin_memcpy(&ulo, &lo, 4);
    __builtin_memcpy(&uhi, &hi, 4);
    return (ulo >> 16) | (uhi & 0xffff0000u);
}

// ---------------- setup: dtype detect + param convert + goff ----------------
__global__ void k_setup(const unsigned short* node_u16, int* flag,
                        const void* bcomb, const void* cbias, const void* gw,
                        const void* gb, const void* gms,
                        float* bcombF, float* cbiasF, float* gwF, float* gbF, float* gmsF,
                        const int* batch, int* goff) {
    if (blockIdx.x == 0) {
        __shared__ int cnt;
        if (threadIdx.x == 0) cnt = 0;
        __syncthreads();
        int local = 0;
        #pragma unroll
        for (int j = 0; j < 4; j++) {
            int idx = 2 * (threadIdx.x * 4 + j);   // EVEN u16 of f32 = mantissa garbage
            unsigned short u = node_u16[idx];
            int e = (u >> 7) & 0xFF;
            if (e < 100 || e > 140) local++;
        }
        atomicAdd(&cnt, local);
        __syncthreads();
        int isf = (cnt > 256) ? 1 : 0;
        if (threadIdx.x == 0) flag[0] = isf;
        int d = threadIdx.x;
        auto rd = [&](const void* p, int i) -> float {
            return isf ? ((const float*)p)[i] : b2f(((const unsigned short*)p)[i]);
        };
        if (d < HC) bcombF[d] = rd(bcomb, d);
        cbiasF[d] = rd(cbias, d);
        gwF[d] = rd(gw, d);
        gbF[d] = rd(gb, d);
        gmsF[d] = rd(gms, d);
    } else {
        int g = threadIdx.x;
        if (g > GG) return;
        int lo = 0, hi = NN;
        while (lo < hi) { int mid = (lo + hi) >> 1; if (batch[mid] < g) lo = mid + 1; else hi = mid; }
        goff[g] = lo;
    }
}

// ---------------- per-(chunk,range) LDS histogram -> partial[c][n] ----------------
__global__ __launch_bounds__(256) void k_ehist(const int* ei, int* partial) {
    __shared__ int hist[RS];
    int c = blockIdx.x, r = blockIdx.y;
    for (int i = threadIdx.x; i < RS; i += 256) hist[i] = 0;
    __syncthreads();
    int base = r * RS;
    const int* dstp = ei + EE + (size_t)c * CS;
    for (int i = threadIdx.x; i < CS; i += 256) {
        int d = dstp[i] - base;
        if ((unsigned)d < RS) atomicAdd(&hist[d], 1);
    }
    __syncthreads();
    int* o = partial + (size_t)c * NN + base;
    for (int i = threadIdx.x; i < RS; i += 256) o[i] = hist[i];
}

// ---------------- per-node exclusive scan over chunks + deg ----------------
__global__ void k_colscan(int* partial, int* deg) {
    int n = blockIdx.x * 256 + threadIdx.x;
    if (n >= NN) return;
    int run = 0;
    for (int c = 0; c < CC; c++) {
        size_t idx = (size_t)c * NN + n;
        int v = partial[idx];
        partial[idx] = run;
        run += v;
    }
    deg[n] = run + 1;   // +1 self-loop
}

// ---------------- block scan for row_off ----------------
__global__ void k_scan1(const int* deg, int* bsum) {
    __shared__ int lds[256];
    int b = blockIdx.x, t = threadIdx.x;
    int base = b * 1024 + t * 4;
    int s = 0;
    #pragma unroll
    for (int j = 0; j < 4; j++) { int idx = base + j; if (idx < NN) s += deg[idx]; }
    lds[t] = s; __syncthreads();
    for (int ofs = 128; ofs > 0; ofs >>= 1) {
        if (t < ofs) lds[t] += lds[t + ofs];
        __syncthreads();
    }
    if (t == 0) bsum[b] = lds[0];
}

__global__ void k_scan2(const int* bsum, int* bpre, int* row_off) {
    if (threadIdx.x == 0) {
        int r = 0;
        for (int i = 0; i < NB; i++) { bpre[i] = r; r += bsum[i]; }
        row_off[NN] = r;
    }
}

__global__ void k_scan3(const int* deg, const int* bpre, int* row_off, float* dinv, int* csr) {
    __shared__ int lds[256];
    int b = blockIdx.x, t = threadIdx.x;
    int base = b * 1024 + t * 4;
    int d[4]; int s = 0;
    #pragma unroll
    for (int j = 0; j < 4; j++) { int idx = base + j; d[j] = (idx < NN) ? deg[idx] : 0; s += d[j]; }
    lds[t] = s; __syncthreads();
    for (int ofs = 1; ofs < 256; ofs <<= 1) {
        int add = (t >= ofs) ? lds[t - ofs] : 0;
        __syncthreads();
        lds[t] += add;
        __syncthreads();
    }
    int excl = lds[t] - s + bpre[b];
    #pragma unroll
    for (int j = 0; j < 4; j++) {
        int idx = base + j;
        if (idx < NN) {
            row_off[idx] = excl;
            csr[excl] = idx;             // self-loop in slot 0 of each row
            excl += d[j];
            dinv[idx] = rsqrtf((float)deg[idx]);
        }
    }
}

// ---------------- deterministic scatter: LDS cursors only ----------------
__global__ __launch_bounds__(256) void k_escatter(const int* ei, const int* row_off,
                                                  const int* partial, int* csr) {
    __shared__ int cur[RS];
    int c = blockIdx.x, r = blockIdx.y;
    int base = r * RS;
    const int* po = partial + (size_t)c * NN + base;
    const int* ro = row_off + base;
    for (int i = threadIdx.x; i < RS; i += 256) cur[i] = ro[i] + 1 + po[i];
    __syncthreads();
    const int* srcp = ei + (size_t)c * CS;
    const int* dstp = ei + EE + (size_t)c * CS;
    for (int i = threadIdx.x; i < CS; i += 256) {
        int d = dstp[i] - base;
        if ((unsigned)d < RS) {
            int slot = atomicAdd(&cur[d], 1);
            csr[slot] = srcp[i];
        }
    }
}

// ---------------- pack W (bases|comb) into MFMA B-fragment layout ----------------
__global__ void k_pack(const int* flag, const void* Wb, const void* Wc, unsigned short* wpack) {
    int t = blockIdx.x, kc = blockIdx.y, lane = threadIdx.x;
    int isf = flag[0];
    int n = t * 16 + (lane & 15);
    int kb = kc * 32 + (lane >> 4) * 8;
    unsigned short* o = wpack + (size_t)(((t * KCN) + kc) * 64 + lane) * 8;
    #pragma unroll
    for (int j = 0; j < 8; j++) {
        int k = kb + j;
        int src = (n < BF) ? (k * BF + n) : (k * HC + (n - BF));
        const void* W = (n < BF) ? Wb : Wc;
        o[j] = isf ? f2b(((const float*)W)[src]) : ((const unsigned short*)W)[src];
    }
}

// ---------------- fused GEMM -> bases[N,128] bf16 + comb[N,96] f32 ----------------
__global__ __launch_bounds__(256) void k_gemm(const int* flag, const void* node,
                                              const unsigned short* wpack, const float* bcombF,
                                              unsigned short* bases, float* comb) {
    int wv = threadIdx.x >> 6, lane = threadIdx.x & 63;
    int row0 = blockIdx.x * 64 + wv * 16;
    int m = row0 + (lane & 15);
    int mc = m < NN ? m : NN - 1;
    int kg = lane >> 4;
    int isf = flag[0];
    const s16x8* bp = reinterpret_cast<const s16x8*>(wpack);
    f32x4 acc[NT];
    #pragma unroll
    for (int t = 0; t < NT; t++) acc[t] = (f32x4){0.f, 0.f, 0.f, 0.f};
    if (isf) {
        const float* nf = (const float*)node + (size_t)mc * DD;
        for (int kc = 0; kc < KCN; kc++) {
            const f32x4* src = reinterpret_cast<const f32x4*>(nf + kc * 32 + kg * 8);
            f32x4 x0 = src[0], x1 = src[1];
            union { s16x8 v; unsigned u[4]; } a;
            a.u[0] = pack_trunc(x0[0], x0[1]);
            a.u[1] = pack_trunc(x0[2], x0[3]);
            a.u[2] = pack_trunc(x1[0], x1[1]);
            a.u[3] = pack_trunc(x1[2], x1[3]);
            #pragma unroll
            for (int t = 0; t < NT; t++) {
                s16x8 b = bp[(size_t)(t * KCN + kc) * 64 + lane];
                acc[t] = __builtin_amdgcn_mfma_f32_16x16x32_bf16(a.v, b, acc[t], 0, 0, 0);
            }
        }
    } else {
        const s16x8* ap = reinterpret_cast<const s16x8*>(node);
        for (int kc = 0; kc < KCN; kc++) {
            s16x8 a = ap[(size_t)mc * 32 + kc * 4 + kg];
            #pragma unroll
            for (int t = 0; t < NT; t++) {
                s16x8 b = bp[(size_t)(t * KCN + kc) * 64 + lane];
                acc[t] = __builtin_amdgcn_mfma_f32_16x16x32_bf16(a, b, acc[t], 0, 0, 0);
            }
        }
    }
    int colb = lane & 15;
    #pragma unroll
    for (int t = 0; t < NT; t++) {
        int nc = t * 16 + colb;
        #pragma unroll
        for (int i = 0; i < 4; i++) {
            int r = row0 + kg * 4 + i;
            if (r < NN) {
                float v = acc[t][i];
                if (nc < BF) bases[(size_t)r * BF + nc] = f2b(v);
                else comb[(size_t)r * HC + (nc - BF)] = v + bcombF[nc - BF];
            }
        }
    }
}

// ---------------- per-node aggregation + einsum -> h (staged in d_out) ----------------
__global__ __launch_bounds__(256) void k_agg(const int* flag, const unsigned short* bases,
                                             const float* comb, const float* dinv,
                                             const int* row_off, const int* csr,
                                             const float* cbiasF, void* hout) {
    __shared__ float2 lds[4][3][64];
    int wv = threadIdx.x >> 6, lane = threadIdx.x & 63;
    int v = blockIdx.x * 4 + wv;          // NN % 4 == 0
    int r0 = row_off[v], r1 = row_off[v + 1];
    float dv = dinv[v];
    const unsigned* bp = reinterpret_cast<const unsigned*>(bases);
    float sy0 = 0.f, sy1 = 0.f, su0 = 0.f, su1 = 0.f;
    float mx0 = -3.4e38f, mx1 = -3.4e38f;
    for (int base = r0; base < r1; base += 64) {
        int nload = r1 - base; if (nload > 64) nload = 64;
        int sidx = 0; float wgt = 0.f;
        if (lane < nload) { sidx = csr[base + lane]; wgt = dinv[sidx] * dv; }
        int j = 0;
        for (; j + 4 <= nload; j += 4) {
            int s0 = __shfl(sidx, j),     s1 = __shfl(sidx, j + 1);
            int s2 = __shfl(sidx, j + 2), s3 = __shfl(sidx, j + 3);
            float w0 = __shfl(wgt, j),     w1 = __shfl(wgt, j + 1);
            float w2 = __shfl(wgt, j + 2), w3 = __shfl(wgt, j + 3);
            unsigned g0 = bp[(size_t)s0 * 64 + lane];
            unsigned g1 = bp[(size_t)s1 * 64 + lane];
            unsigned g2 = bp[(size_t)s2 * 64 + lane];
            unsigned g3 = bp[(size_t)s3 * 64 + lane];
            float a, b;
            a = b2f(g0 & 0xffffu); b = b2f(g0 >> 16);
            sy0 += w0 * a; sy1 += w0 * b; su0 += a; su1 += b; mx0 = fmaxf(mx0, a); mx1 = fmaxf(mx1, b);
            a = b2f(g1 & 0xffffu); b = b2f(g1 >> 16);
            sy0 += w1 * a; sy1 += w1 * b; su0 += a; su1 += b; mx0 = fmaxf(mx0, a); mx1 = fmaxf(mx1, b);
            a = b2f(g2 & 0xffffu); b = b2f(g2 >> 16);
            sy0 += w2 * a; sy1 += w2 * b; su0 += a; su1 += b; mx0 = fmaxf(mx0, a); mx1 = fmaxf(mx1, b);
            a = b2f(g3 & 0xffffu); b = b2f(g3 >> 16);
            sy0 += w3 * a; sy1 += w3 * b; su0 += a; su1 += b; mx0 = fmaxf(mx0, a); mx1 = fmaxf(mx1, b);
        }
        for (; j < nload; j++) {
            int s0 = __shfl(sidx, j); float w0 = __shfl(wgt, j);
            unsigned g0 = bp[(size_t)s0 * 64 + lane];
            float a = b2f(g0 & 0xffffu), b = b2f(g0 >> 16);
            sy0 += w0 * a; sy1 += w0 * b; su0 += a; su1 += b; mx0 = fmaxf(mx0, a); mx1 = fmaxf(mx1, b);
        }
    }
    lds[wv][0][lane] = (float2){sy0, sy1};
    lds[wv][1][lane] = (float2){su0, su1};
    lds[wv][2][lane] = (float2){mx0, mx1};
    __syncthreads();
    const float* P0 = (const float*)&lds[wv][0][0];
    const float* P1 = (const float*)&lds[wv][1][0];
    const float* P2 = (const float*)&lds[wv][2][0];
    int d0 = lane * 4;
    int hh = d0 >> 5;
    float cb[12];
    #pragma unroll
    for (int k = 0; k < 12; k++) cb[k] = comb[(size_t)v * HC + hh * 12 + k];
    float y[4];
    #pragma unroll
    for (int i = 0; i < 4; i++) {
        int d = d0 + i, f = d & 31;
        float acc = cbiasF[d];
        #pragma unroll
        for (int k = 0; k < 12; k++) {
            int a = k >> 2, b = k & 3;
            const float* P = (a == 0) ? P0 : ((a == 1) ? P1 : P2);
            acc += cb[k] * P[b * 32 + f];
        }
        y[i] = acc;
    }
    if (flag[0]) {
        f32x4 o = {y[0], y[1], y[2], y[3]};
        reinterpret_cast<f32x4*>(hout)[(size_t)v * 64 + lane] = o;
    } else {
        union { unsigned short e[4]; uint2 u; } o;
        #pragma unroll
        for (int i = 0; i < 4; i++) o.e[i] = f2b(y[i]);
        reinterpret_cast<uint2*>(hout)[(size_t)v * 64 + lane] = o.u;
    }
}

// ---------------- GraphNorm stats pass 1: atomic-free sliced reduction ----------------
__global__ void k_stats1(const int* flag, const void* h, const int* goff, float* sstat) {
    int g = blockIdx.x, s = blockIdx.y, t = threadIdx.x;
    int isf = flag[0];
    int v0 = goff[g], v1 = goff[g + 1];
    float sum = 0.f, sq = 0.f;
    if (isf) {
        const float* hf = (const float*)h;
        for (int v = v0 + s; v < v1; v += SL) {
            float x = hf[(size_t)v * DD + t];
            sum += x; sq += x * x;
        }
    } else {
        const unsigned short* hb = (const unsigned short*)h;
        for (int v = v0 + s; v < v1; v += SL) {
            float x = b2f(hb[(size_t)v * DD + t]);
            sum += x; sq += x * x;
        }
    }
    size_t o = ((size_t)(g * SL + s)) * (2 * DD);
    sstat[o + t] = sum;
    sstat[o + DD + t] = sq;
}

// ---------------- GraphNorm stats pass 2: fold slices, compute scale/shift ----------------
__global__ void k_stats2(const float* sstat, const int* goff,
                         const float* gwF, const float* gbF, const float* gmsF,
                         float* sA, float* sB) {
    int g = blockIdx.x, d = threadIdx.x;
    float sum = 0.f, sq = 0.f;
    #pragma unroll
    for (int s = 0; s < SL; s++) {
        size_t o = ((size_t)(g * SL + s)) * (2 * DD);
        sum += sstat[o + d];
        sq  += sstat[o + DD + d];
    }
    int c = goff[g + 1] - goff[g];
    float cnt = (float)(c > 1 ? c : 1);
    float mu = sum / cnt;
    float m2 = sq / cnt;
    float al = gmsF[d];
    float var = m2 - mu * mu * (2.f * al - al * al);   // E[(h-al*mu)^2]
    float rstd = rsqrtf(var + 1e-5f);
    float sa = gwF[d] * rstd;
    sA[g * DD + d] = sa;
    sB[g * DD + d] = gbF[d] - sa * al * mu;
}

// ---------------- final normalize + ReLU (in place on d_out) ----------------
__global__ void k_out(const int* flag, const int* batch, const float* sA, const float* sB, void* out) {
    int tid = blockIdx.x * 256 + threadIdx.x;
    int v = tid >> 6, q = tid & 63;
    if (v >= NN) return;
    int g = batch[v];
    f32x4 a = reinterpret_cast<const f32x4*>(sA)[g * 64 + q];
    f32x4 b = reinterpret_cast<const f32x4*>(sB)[g * 64 + q];
    if (flag[0]) {
        f32x4 x = reinterpret_cast<const f32x4*>(out)[(size_t)v * 64 + q];
        f32x4 y;
        #pragma unroll
        for (int i = 0; i < 4; i++) y[i] = fmaxf(x[i] * a[i] + b[i], 0.f);
        reinterpret_cast<f32x4*>(out)[(size_t)v * 64 + q] = y;
    } else {
        uint2 xr = reinterpret_cast<const uint2*>(out)[(size_t)v * 64 + q];
        float x0 = b2f(xr.x & 0xffffu), x1 = b2f(xr.x >> 16);
        float x2 = b2f(xr.y & 0xffffu), x3 = b2f(xr.y >> 16);
        union { unsigned short e[4]; uint2 u; } o;
        o.e[0] = f2b(fmaxf(x0 * a[0] + b[0], 0.f));
        o.e[1] = f2b(fmaxf(x1 * a[1] + b[1], 0.f));
        o.e[2] = f2b(fmaxf(x2 * a[2] + b[2], 0.f));
        o.e[3] = f2b(fmaxf(x3 * a[3] + b[3], 0.f));
        reinterpret_cast<uint2*>(out)[(size_t)v * 64 + q] = o.u;
    }
}

extern "C" void kernel_launch(void* const* d_in, const int* in_sizes, int n_in,
                              void* d_out, int out_size, void* d_ws, size_t ws_size,
                              hipStream_t stream) {
    const void* node  = d_in[0];
    const void* Wb    = d_in[2];
    const void* Wc    = d_in[3];
    const void* bcomb = d_in[4];
    const void* cbias = d_in[5];
    const void* gw    = d_in[6];
    const void* gb    = d_in[7];
    const void* gms   = d_in[8];
    const int* ei     = (const int*)d_in[9];
    const int* batch  = (const int*)d_in[10];

    char* w = (char*)d_ws;
    size_t off = 0;
    auto alloc = [&](size_t bytes) -> void* {
        off = (off + 255) & ~(size_t)255;
        void* p = w + off;
        off += bytes;
        return p;
    };
    unsigned short* bases = (unsigned short*)alloc((size_t)NN * BF * 2);
    float* comb    = (float*)alloc((size_t)NN * HC * 4);
    int*   csr     = (int*)alloc((size_t)(EE + NN) * 4);
    int*   partial = (int*)alloc((size_t)CC * NN * 4);
    int*   deg     = (int*)alloc((size_t)NN * 4);
    float* dinv    = (float*)alloc((size_t)NN * 4);
    int*   row_off = (int*)alloc((size_t)(NN + 1) * 4);
    int*   bsum    = (int*)alloc((size_t)NB * 4);
    int*   bpre    = (int*)alloc((size_t)NB * 4);
    int*   goff    = (int*)alloc((size_t)(GG + 1) * 4);
    float* sstat   = (float*)alloc((size_t)GG * SL * 2 * DD * 4);
    float* sA      = (float*)alloc((size_t)GG * DD * 4);
    float* sB      = (float*)alloc((size_t)GG * DD * 4);
    unsigned short* wpack = (unsigned short*)alloc((size_t)NT * KCN * 64 * 8 * 2);
    int*   flag    = (int*)alloc(256);
    float* bcombF  = (float*)alloc(HC * 4);
    float* cbiasF  = (float*)alloc(DD * 4);
    float* gwF     = (float*)alloc(DD * 4);
    float* gbF     = (float*)alloc(DD * 4);
    float* gmsF    = (float*)alloc(DD * 4);

    k_setup<<<2, 256, 0, stream>>>((const unsigned short*)node, flag, bcomb, cbias, gw, gb, gms,
                                   bcombF, cbiasF, gwF, gbF, gmsF, batch, goff);
    k_ehist<<<dim3(CC, RC), 256, 0, stream>>>(ei, partial);
    k_colscan<<<(NN + 255) / 256, 256, 0, stream>>>(partial, deg);
    k_scan1<<<NB, 256, 0, stream>>>(deg, bsum);
    k_scan2<<<1, 64, 0, stream>>>(bsum, bpre, row_off);
    k_scan3<<<NB, 256, 0, stream>>>(deg, bpre, row_off, dinv, csr);
    k_escatter<<<dim3(CC, RC), 256, 0, stream>>>(ei, row_off, partial, csr);
    k_pack<<<dim3(NT, KCN), 64, 0, stream>>>(flag, Wb, Wc, wpack);
    k_gemm<<<(NN + 63) / 64, 256, 0, stream>>>(flag, node, wpack, bcombF, bases, comb);
    k_agg<<<NN / 4, 256, 0, stream>>>(flag, bases, comb, dinv, row_off, csr, cbiasF, d_out);
    k_stats1<<<dim3(GG, SL), 256, 0, stream>>>(flag, d_out, goff, sstat);
    k_stats2<<<GG, 256, 0, stream>>>(sstat, goff, gwF, gbF, gmsF, sA, sB);
    k_out<<<(NN * 64 + 255) / 256, 256, 0, stream>>>(flag, batch, sA, sB, d_out);
}